// Round 3
// baseline (1869.683 us; speedup 1.0000x reference)
//
#include <hip/hip_runtime.h>
#include <hip/hip_bf16.h>

// RWKV forward, MI355X gfx950.
// GEMMs: bf16 MFMA 16x16x32, global_load_lds(16B), xor-swizzled LDS,
//   single-buffered m97 structure. ALL big GEMMs now 128x128 tiles
//   (4.0 MFMA/staging-load vs 2.67 at 128x64):
//   - k/v/r merged grid.z=3 -> (64,8,3)=1536 blocks
//   - cm_k + cm_r fused one dispatch -> (64,40)=2560 blocks
//   - cm_v split-K=2 via grid.z, unsafeAtomicAdd f32 epilogue -> (64,8,2)
//   o-proj stays 128x64 (lone N=1024, 512-block starvation at 128x128).
// WKV scan: 2-kernel chunked parallel scan (comb folded into out kernel).
// Layer-0 reads xin directly; o-proj MODE 6 writes xres = xin + acc (no memcpy).

#define LNUM 4
#define BSZ  4
#define TSZ  2048
#define CSZ  1024
#define FFND 4096
#define MROWS (BSZ*TSZ)
#define EPSF 1e-5f

typedef __hip_bfloat16 bf16;
typedef __bf16 bf16x8 __attribute__((ext_vector_type(8)));
typedef float f32x4 __attribute__((ext_vector_type(4)));

#define BM 128
#define BK 64

// scan chunking
#define SCK  64
#define SLEN (TSZ/SCK)   // 32

__device__ __forceinline__ void async_copy16(const void* g, void* l) {
    __builtin_amdgcn_global_load_lds((const __attribute__((address_space(1))) void*)g,
                                     (__attribute__((address_space(3))) void*)l, 16, 0, 0);
}

// ---- shared GEMM body ----
// C[M,N] = A[M,K] * Bw[N,K]^T, bf16 row-major (row stride LDK; K = depth of this
// split; grid.z selects K-offset z*K). TBN=128: 4 waves 2x2 of 64x64.
// TBN=64: 4 waves 4x1 of 32x64. MODE epilogues:
// 2: out f32 += acc              3: out bf16 = relu(acc)^2
// 4: out bf16 = sigmoid(acc)     5: out f32 += (float)auxbf[idx] * acc
// 6: out f32 = auxf32[idx] + acc 7: atomicAdd(out f32, (float)auxbf[idx] * acc)
template<int MODE, int TBN>
__launch_bounds__(256)
__global__ void gemm_bt(const bf16* __restrict__ A, const bf16* __restrict__ Bw,
                        void* __restrict__ outp, const bf16* __restrict__ aux,
                        int K, int LDK, int N)
{
    constexpr int MT  = (TBN == 128) ? 4 : 2;   // 16-row tiles per wave
    constexpr int NBI = TBN / 32;               // B staging issues per thread
    __shared__ __align__(16) __bf16 sA[BM*BK];
    __shared__ __align__(16) __bf16 sB[TBN*BK];
    const int tid  = threadIdx.x;
    const int lane = tid & 63;
    const int wid  = tid >> 6;
    const int wmB  = (TBN == 128) ? (wid >> 1) * 64 : wid * 32;  // wave row base
    const int wnB  = (TBN == 128) ? (wid & 1) * 64 : 0;          // wave col base
    const size_t bm0 = (size_t)blockIdx.x * BM;
    const size_t bn0 = (size_t)blockIdx.y * TBN;
    const size_t koff = (size_t)blockIdx.z * K;

    // staging: 8 lanes/row, 8 chunks of 16B per 64-elem row; xor swizzle.
    const int lrow8 = lane >> 3;
    const int cbg   = (lane & 7) ^ lrow8;

    const bf16* pA[4]; const bf16* pB[NBI];
#pragma unroll
    for (int i = 0; i < 4; ++i)
        pA[i] = A + (bm0 + (i*4 + wid)*8 + lrow8) * (size_t)LDK + koff + cbg*8;
#pragma unroll
    for (int i = 0; i < NBI; ++i)
        pB[i] = Bw + (bn0 + (i*4 + wid)*8 + lrow8) * (size_t)LDK + koff + cbg*8;

    f32x4 acc[MT][4];
#pragma unroll
    for (int a = 0; a < MT; ++a)
#pragma unroll
        for (int b = 0; b < 4; ++b) acc[a][b] = (f32x4){0.f,0.f,0.f,0.f};

    const int q   = lane >> 4;
    const int rlo = lane & 15;

    const int ktiles = K / BK;
    for (int kt = 0; kt < ktiles; ++kt) {
#pragma unroll
        for (int i = 0; i < 4; ++i) {
            async_copy16(pA[i], &sA[(i*4 + wid)*8*BK]);
            pA[i] += BK;
        }
#pragma unroll
        for (int i = 0; i < NBI; ++i) {
            async_copy16(pB[i], &sB[(i*4 + wid)*8*BK]);
            pB[i] += BK;
        }
        __syncthreads();
#pragma unroll
        for (int ks = 0; ks < 2; ++ks) {
            bf16x8 aF[MT], bF[4];
#pragma unroll
            for (int mt = 0; mt < MT; ++mt) {
                const int r  = wmB + mt*16 + rlo;
                const int cb = (ks*4 + q) ^ (r & 7);
                aF[mt] = *(const bf16x8*)&sA[r*BK + cb*8];
            }
#pragma unroll
            for (int nt = 0; nt < 4; ++nt) {
                const int r  = wnB + nt*16 + rlo;
                const int cb = (ks*4 + q) ^ (r & 7);
                bF[nt] = *(const bf16x8*)&sB[r*BK + cb*8];
            }
#pragma unroll
            for (int mt = 0; mt < MT; ++mt)
#pragma unroll
                for (int nt = 0; nt < 4; ++nt)
                    acc[mt][nt] = __builtin_amdgcn_mfma_f32_16x16x32_bf16(
                        aF[mt], bF[nt], acc[mt][nt], 0, 0, 0);
        }
        __syncthreads();
    }

    // C/D layout: col = lane&15, row = (lane>>4)*4 + reg
#pragma unroll
    for (int mt = 0; mt < MT; ++mt) {
#pragma unroll
        for (int nt = 0; nt < 4; ++nt) {
            const size_t col = bn0 + wnB + nt*16 + rlo;
#pragma unroll
            for (int i = 0; i < 4; ++i) {
                const size_t row = bm0 + wmB + mt*16 + q*4 + i;
                const size_t idx = row * (size_t)N + col;
                const float v = acc[mt][nt][i];
                if (MODE == 2) {
                    ((float*)outp)[idx] += v;
                } else if (MODE == 3) {
                    const float t = fmaxf(v, 0.f);
                    ((bf16*)outp)[idx] = __float2bfloat16(t*t);
                } else if (MODE == 4) {
                    ((bf16*)outp)[idx] = __float2bfloat16(1.f/(1.f+__expf(-v)));
                } else if (MODE == 6) {
                    ((float*)outp)[idx] = ((const float*)aux)[idx] + v;
                } else if (MODE == 7) {
                    unsafeAtomicAdd(&((float*)outp)[idx], (float)aux[idx] * v);
                } else {
                    ((float*)outp)[idx] += (float)aux[idx] * v;
                }
            }
        }
    }
}

// k/v/r GEMMs merged: grid.z selects {A,W,out}; z==2 applies sigmoid. 128x128 tile.
__launch_bounds__(256)
__global__ void gemm_kvr(const bf16* __restrict__ A0, const bf16* __restrict__ A1,
                         const bf16* __restrict__ A2,
                         const bf16* __restrict__ W0, const bf16* __restrict__ W1,
                         const bf16* __restrict__ W2,
                         bf16* __restrict__ O0, bf16* __restrict__ O1,
                         bf16* __restrict__ O2)
{
    constexpr int MT = 4, NBI = 4, K = CSZ, N = CSZ;
    const int z = blockIdx.z;
    const bf16* A  = (z == 0) ? A0 : (z == 1) ? A1 : A2;
    const bf16* Bw = (z == 0) ? W0 : (z == 1) ? W1 : W2;
    bf16* outp     = (z == 0) ? O0 : (z == 1) ? O1 : O2;

    __shared__ __align__(16) __bf16 sA[BM*BK];
    __shared__ __align__(16) __bf16 sB[128*BK];
    const int tid  = threadIdx.x;
    const int lane = tid & 63;
    const int wid  = tid >> 6;
    const int wmB  = (wid >> 1) * 64;
    const int wnB  = (wid & 1) * 64;
    const size_t bm0 = (size_t)blockIdx.x * BM;
    const size_t bn0 = (size_t)blockIdx.y * 128;

    const int lrow8 = lane >> 3;
    const int cbg   = (lane & 7) ^ lrow8;

    const bf16* pA[4]; const bf16* pB[NBI];
#pragma unroll
    for (int i = 0; i < 4; ++i)
        pA[i] = A + (bm0 + (i*4 + wid)*8 + lrow8) * (size_t)K + cbg*8;
#pragma unroll
    for (int i = 0; i < NBI; ++i)
        pB[i] = Bw + (bn0 + (i*4 + wid)*8 + lrow8) * (size_t)K + cbg*8;

    f32x4 acc[MT][4];
#pragma unroll
    for (int a = 0; a < MT; ++a)
#pragma unroll
        for (int b = 0; b < 4; ++b) acc[a][b] = (f32x4){0.f,0.f,0.f,0.f};

    const int q   = lane >> 4;
    const int rlo = lane & 15;

    for (int kt = 0; kt < K/BK; ++kt) {
#pragma unroll
        for (int i = 0; i < 4; ++i) {
            async_copy16(pA[i], &sA[(i*4 + wid)*8*BK]);
            pA[i] += BK;
        }
#pragma unroll
        for (int i = 0; i < NBI; ++i) {
            async_copy16(pB[i], &sB[(i*4 + wid)*8*BK]);
            pB[i] += BK;
        }
        __syncthreads();
#pragma unroll
        for (int ks = 0; ks < 2; ++ks) {
            bf16x8 aF[MT], bF[4];
#pragma unroll
            for (int mt = 0; mt < MT; ++mt) {
                const int r  = wmB + mt*16 + rlo;
                const int cb = (ks*4 + q) ^ (r & 7);
                aF[mt] = *(const bf16x8*)&sA[r*BK + cb*8];
            }
#pragma unroll
            for (int nt = 0; nt < 4; ++nt) {
                const int r  = wnB + nt*16 + rlo;
                const int cb = (ks*4 + q) ^ (r & 7);
                bF[nt] = *(const bf16x8*)&sB[r*BK + cb*8];
            }
#pragma unroll
            for (int mt = 0; mt < MT; ++mt)
#pragma unroll
                for (int nt = 0; nt < 4; ++nt)
                    acc[mt][nt] = __builtin_amdgcn_mfma_f32_16x16x32_bf16(
                        aF[mt], bF[nt], acc[mt][nt], 0, 0, 0);
        }
        __syncthreads();
    }

#pragma unroll
    for (int mt = 0; mt < MT; ++mt) {
#pragma unroll
        for (int nt = 0; nt < 4; ++nt) {
            const size_t col = bn0 + wnB + nt*16 + rlo;
#pragma unroll
            for (int i = 0; i < 4; ++i) {
                const size_t row = bm0 + wmB + mt*16 + q*4 + i;
                float v = acc[mt][nt][i];
                if (z == 2) v = 1.f/(1.f+__expf(-v));
                ((bf16*)outp)[row * (size_t)N + col] = __float2bfloat16(v);
            }
        }
    }
}

// cm_k (N=4096, relu^2) and cm_r (N=1024, sigmoid) fused: blockIdx.y<32 -> cm_k,
// else cm_r. Both 128x128, K=1024. Independent (both read ln2 outputs).
__launch_bounds__(256)
__global__ void gemm_cmkr(const bf16* __restrict__ Ak, const bf16* __restrict__ Ar,
                          const bf16* __restrict__ Wk, const bf16* __restrict__ Wr,
                          bf16* __restrict__ Ok, bf16* __restrict__ Or)
{
    constexpr int MT = 4, NBI = 4, K = CSZ;
    const bool isk = (blockIdx.y < FFND/128);
    const bf16* A  = isk ? Ak : Ar;
    const bf16* Bw = isk ? Wk : Wr;
    bf16* outp     = isk ? Ok : Or;
    const int N    = isk ? FFND : CSZ;
    const size_t bn0 = (size_t)(isk ? blockIdx.y : blockIdx.y - FFND/128) * 128;

    __shared__ __align__(16) __bf16 sA[BM*BK];
    __shared__ __align__(16) __bf16 sB[128*BK];
    const int tid  = threadIdx.x;
    const int lane = tid & 63;
    const int wid  = tid >> 6;
    const int wmB  = (wid >> 1) * 64;
    const int wnB  = (wid & 1) * 64;
    const size_t bm0 = (size_t)blockIdx.x * BM;

    const int lrow8 = lane >> 3;
    const int cbg   = (lane & 7) ^ lrow8;

    const bf16* pA[4]; const bf16* pB[NBI];
#pragma unroll
    for (int i = 0; i < 4; ++i)
        pA[i] = A + (bm0 + (i*4 + wid)*8 + lrow8) * (size_t)K + cbg*8;
#pragma unroll
    for (int i = 0; i < NBI; ++i)
        pB[i] = Bw + (bn0 + (i*4 + wid)*8 + lrow8) * (size_t)K + cbg*8;

    f32x4 acc[MT][4];
#pragma unroll
    for (int a = 0; a < MT; ++a)
#pragma unroll
        for (int b = 0; b < 4; ++b) acc[a][b] = (f32x4){0.f,0.f,0.f,0.f};

    const int q   = lane >> 4;
    const int rlo = lane & 15;

    for (int kt = 0; kt < K/BK; ++kt) {
#pragma unroll
        for (int i = 0; i < 4; ++i) {
            async_copy16(pA[i], &sA[(i*4 + wid)*8*BK]);
            pA[i] += BK;
        }
#pragma unroll
        for (int i = 0; i < NBI; ++i) {
            async_copy16(pB[i], &sB[(i*4 + wid)*8*BK]);
            pB[i] += BK;
        }
        __syncthreads();
#pragma unroll
        for (int ks = 0; ks < 2; ++ks) {
            bf16x8 aF[MT], bF[4];
#pragma unroll
            for (int mt = 0; mt < MT; ++mt) {
                const int r  = wmB + mt*16 + rlo;
                const int cb = (ks*4 + q) ^ (r & 7);
                aF[mt] = *(const bf16x8*)&sA[r*BK + cb*8];
            }
#pragma unroll
            for (int nt = 0; nt < 4; ++nt) {
                const int r  = wnB + nt*16 + rlo;
                const int cb = (ks*4 + q) ^ (r & 7);
                bF[nt] = *(const bf16x8*)&sB[r*BK + cb*8];
            }
#pragma unroll
            for (int mt = 0; mt < MT; ++mt)
#pragma unroll
                for (int nt = 0; nt < 4; ++nt)
                    acc[mt][nt] = __builtin_amdgcn_mfma_f32_16x16x32_bf16(
                        aF[mt], bF[nt], acc[mt][nt], 0, 0, 0);
        }
        __syncthreads();
    }

#pragma unroll
    for (int mt = 0; mt < MT; ++mt) {
#pragma unroll
        for (int nt = 0; nt < 4; ++nt) {
            const size_t col = bn0 + wnB + nt*16 + rlo;
#pragma unroll
            for (int i = 0; i < 4; ++i) {
                const size_t row = bm0 + wmB + mt*16 + q*4 + i;
                const float v = acc[mt][nt][i];
                float o;
                if (isk) { const float t = fmaxf(v, 0.f); o = t*t; }
                else     { o = 1.f/(1.f+__expf(-v)); }
                ((bf16*)outp)[row * (size_t)N + col] = __float2bfloat16(o);
            }
        }
    }
}

// Fused LayerNorm + time_shift + token mixes. Block = one (b,t) row, 256 thr x 4 ch.
template<int NOUT>
__launch_bounds__(256)
__global__ void ln_mix_kernel(const float* __restrict__ x, const float* __restrict__ lnw,
                              const float* __restrict__ mka, const float* __restrict__ mva,
                              const float* __restrict__ mra,
                              bf16* __restrict__ ok, bf16* __restrict__ ov, bf16* __restrict__ orr)
{
    const int bt  = blockIdx.x;
    const int t   = bt % TSZ;
    const int tid = threadIdx.x;
    const float4 xc = ((const float4*)(x + (size_t)bt*CSZ))[tid];
    float4 xp = {0.f,0.f,0.f,0.f};
    const bool hasp = (t != 0);
    if (hasp) xp = ((const float4*)(x + (size_t)(bt-1)*CSZ))[tid];

    float s0 = xc.x+xc.y+xc.z+xc.w;
    float s1 = xc.x*xc.x+xc.y*xc.y+xc.z*xc.z+xc.w*xc.w;
    float s2 = xp.x+xp.y+xp.z+xp.w;
    float s3 = xp.x*xp.x+xp.y*xp.y+xp.z*xp.z+xp.w*xp.w;
#pragma unroll
    for (int off = 32; off > 0; off >>= 1) {
        s0 += __shfl_down(s0, off); s1 += __shfl_down(s1, off);
        s2 += __shfl_down(s2, off); s3 += __shfl_down(s3, off);
    }
    __shared__ float red[4][4];
    if ((tid & 63) == 0) { const int wq = tid >> 6;
        red[wq][0]=s0; red[wq][1]=s1; red[wq][2]=s2; red[wq][3]=s3; }
    __syncthreads();
    s0 = red[0][0]+red[1][0]+red[2][0]+red[3][0];
    s1 = red[0][1]+red[1][1]+red[2][1]+red[3][1];
    s2 = red[0][2]+red[1][2]+red[2][2]+red[3][2];
    s3 = red[0][3]+red[1][3]+red[2][3]+red[3][3];

    const float inv = 1.f/CSZ;
    const float muC = s0*inv;
    const float rsC = rsqrtf(s1*inv - muC*muC + EPSF);
    const float muP = s2*inv;
    const float rsP = rsqrtf(s3*inv - muP*muP + EPSF);

    const int c4 = tid*4;
    const float4 lw = ((const float4*)lnw)[tid];
    const float4 mk = ((const float4*)mka)[tid];
    const float4 mv = (NOUT >= 2) ? ((const float4*)mva)[tid] : lw;
    const float4 mr = (NOUT >= 3) ? ((const float4*)mra)[tid] : lw;

    float hcv[4] = {(xc.x-muC)*rsC*lw.x, (xc.y-muC)*rsC*lw.y,
                    (xc.z-muC)*rsC*lw.z, (xc.w-muC)*rsC*lw.w};
    float hpv[4];
    if (hasp) {
        hpv[0]=(xp.x-muP)*rsP*lw.x; hpv[1]=(xp.y-muP)*rsP*lw.y;
        hpv[2]=(xp.z-muP)*rsP*lw.z; hpv[3]=(xp.w-muP)*rsP*lw.w;
    } else { hpv[0]=hpv[1]=hpv[2]=hpv[3]=0.f; }
    const float mkv[4]={mk.x,mk.y,mk.z,mk.w};
    const float mvv[4]={mv.x,mv.y,mv.z,mv.w};
    const float mrv[4]={mr.x,mr.y,mr.z,mr.w};

    __align__(8) bf16 o0[4], o1[4], o2[4];
#pragma unroll
    for (int j = 0; j < 4; ++j) {
        o0[j] = __float2bfloat16(hcv[j]*mkv[j] + hpv[j]*(1.f-mkv[j]));
        if (NOUT >= 2) o1[j] = __float2bfloat16(hcv[j]*mvv[j] + hpv[j]*(1.f-mvv[j]));
        if (NOUT >= 3) o2[j] = __float2bfloat16(hcv[j]*mrv[j] + hpv[j]*(1.f-mrv[j]));
    }
    *(uint2*)(ok + (size_t)bt*CSZ + c4) = *(const uint2*)o0;
    if (NOUT >= 2) *(uint2*)(ov  + (size_t)bt*CSZ + c4) = *(const uint2*)o1;
    if (NOUT >= 3) *(uint2*)(orr + (size_t)bt*CSZ + c4) = *(const uint2*)o2;
}

// ---- WKV 2-kernel chunked parallel scan, channels-along-lanes ----
__launch_bounds__(256)
__global__ void wkv_sum_kernel(const bf16* __restrict__ kb, const bf16* __restrict__ vb,
                               const float* __restrict__ td,
                               float* __restrict__ sN, float* __restrict__ sD,
                               float* __restrict__ sM)
{
    const int j  = blockIdx.x;
    const int b  = blockIdx.y >> 2;
    const int cg = blockIdx.y & 3;
    const int c  = cg*256 + threadIdx.x;
    const float w = -__expf(td[c]);

    size_t idx = ((size_t)b*TSZ + j*SLEN)*CSZ + c;
    float num = 0.f, den = 0.f, mx = -1e38f;
    float kt = (float)kb[idx], vt = (float)vb[idx];
    for (int t = 0; t < SLEN; ++t) {
        float kn = 0.f, vn = 0.f;
        if (t + 1 < SLEN) {
            kn = (float)kb[idx + CSZ]; vn = (float)vb[idx + CSZ];
        }
        const float ms = fmaxf(mx + w, kt);
        const float p1 = __expf(mx + w - ms);
        const float p2 = __expf(kt - ms);
        num = p1*num + p2*vt; den = p1*den + p2; mx = ms;
        idx += CSZ; kt = kn; vt = vn;
    }
    const size_t sidx = ((size_t)b*SCK + j)*CSZ + c;
    sN[sidx] = num; sD[sidx] = den; sM[sidx] = mx;
}

// Out kernel computes its own exclusive prefix over chunk summaries (comb folded in).
__launch_bounds__(256)
__global__ void wkv_out_kernel(const bf16* __restrict__ kb, const bf16* __restrict__ vb,
                               const bf16* __restrict__ rb,
                               const float* __restrict__ td, const float* __restrict__ tf,
                               const float* __restrict__ sN, const float* __restrict__ sD,
                               const float* __restrict__ sM,
                               bf16* __restrict__ outb)
{
    const int j  = blockIdx.x;
    const int b  = blockIdx.y >> 2;
    const int cg = blockIdx.y & 3;
    const int c  = cg*256 + threadIdx.x;
    const float w = -__expf(td[c]);
    const float u = tf[c];
    const float wL = w * (float)SLEN;

    // exclusive prefix over chunks 0..j-1
    float num = 0.f, den = 0.f, mx = -1e38f;
    size_t pidx = (size_t)b*SCK*CSZ + c;
    for (int jj = 0; jj < j; ++jj) {
        const float nl = sN[pidx], dl = sD[pidx], ml = sM[pidx];
        const float mi = mx + wL;
        const float mo = fmaxf(mi, ml);
        const float e1 = __expf(mi - mo);
        const float e2 = __expf(ml - mo);
        num = e1*num + e2*nl; den = e1*den + e2*dl; mx = mo;
        pidx += CSZ;
    }

    size_t idx = ((size_t)b*TSZ + j*SLEN)*CSZ + c;
    float kt = (float)kb[idx], vt = (float)vb[idx], rt = (float)rb[idx];
    for (int t = 0; t < SLEN; ++t) {
        float kn = 0.f, vn = 0.f, rn = 0.f;
        if (t + 1 < SLEN) {
            kn = (float)kb[idx + CSZ]; vn = (float)vb[idx + CSZ]; rn = (float)rb[idx + CSZ];
        }
        const float ku = kt + u;
        const float mo = fmaxf(mx, ku);
        const float e1 = __expf(mx - mo);
        const float e2 = __expf(ku - mo);
        const float outv = (e1*num + e2*vt) / (e1*den + e2);
        const float ms = fmaxf(mx + w, kt);
        const float p1 = __expf(mx + w - ms);
        const float p2 = __expf(kt - ms);
        num = p1*num + p2*vt; den = p1*den + p2; mx = ms;
        outb[idx] = __float2bfloat16(rt * outv);
        idx += CSZ; kt = kn; vt = vn; rt = rn;
    }
}

__launch_bounds__(256)
__global__ void final_ln_kernel(const float* __restrict__ x, const float* __restrict__ lnw,
                                float* __restrict__ out)
{
    const int bt  = blockIdx.x;
    const int tid = threadIdx.x;
    const float4 xc = ((const float4*)(x + (size_t)bt*CSZ))[tid];
    float s0 = xc.x+xc.y+xc.z+xc.w;
    float s1 = xc.x*xc.x+xc.y*xc.y+xc.z*xc.z+xc.w*xc.w;
#pragma unroll
    for (int off = 32; off > 0; off >>= 1) {
        s0 += __shfl_down(s0, off); s1 += __shfl_down(s1, off);
    }
    __shared__ float red[4][2];
    if ((tid & 63) == 0) { red[tid>>6][0] = s0; red[tid>>6][1] = s1; }
    __syncthreads();
    s0 = red[0][0]+red[1][0]+red[2][0]+red[3][0];
    s1 = red[0][1]+red[1][1]+red[2][1]+red[3][1];
    const float inv = 1.f/CSZ;
    const float mu = s0*inv;
    const float rs = rsqrtf(s1*inv - mu*mu + EPSF);
    const float4 lw = ((const float4*)lnw)[tid];
    float4 o;
    o.x = (xc.x-mu)*rs*lw.x; o.y = (xc.y-mu)*rs*lw.y;
    o.z = (xc.z-mu)*rs*lw.z; o.w = (xc.w-mu)*rs*lw.w;
    ((float4*)(out + (size_t)bt*CSZ))[tid] = o;
}

// One fused per-layer weight conversion (7 tensors -> bf16). Units of 4 elems.
#define N4_CC (CSZ*CSZ/4)
#define N4_FC (FFND*CSZ/4)
__global__ void cvt_weights_kernel(const float* __restrict__ tk, const float* __restrict__ tv,
                                   const float* __restrict__ tr, const float* __restrict__ to,
                                   const float* __restrict__ ck, const float* __restrict__ cv,
                                   const float* __restrict__ cr,
                                   bf16* __restrict__ wk, bf16* __restrict__ wv,
                                   bf16* __restrict__ wr, bf16* __restrict__ wo,
                                   bf16* __restrict__ wck, bf16* __restrict__ wcv,
                                   bf16* __restrict__ wcr)
{
    int i = blockIdx.x * 256 + threadIdx.x;
    const float* s; bf16* d;
    if      (i < 1*N4_CC)          { s = tk; d = wk;  }
    else if (i < 2*N4_CC)          { s = tv; d = wv;  i -= 1*N4_CC; }
    else if (i < 3*N4_CC)          { s = tr; d = wr;  i -= 2*N4_CC; }
    else if (i < 4*N4_CC)          { s = to; d = wo;  i -= 3*N4_CC; }
    else if (i < 4*N4_CC+N4_FC)    { s = ck; d = wck; i -= 4*N4_CC; }
    else if (i < 4*N4_CC+2*N4_FC)  { s = cv; d = wcv; i -= 4*N4_CC+N4_FC; }
    else                           { s = cr; d = wcr; i -= 4*N4_CC+2*N4_FC; }
    const float4 f = ((const float4*)s)[i];
    __align__(8) bf16 o[4] = {__float2bfloat16(f.x), __float2bfloat16(f.y),
                              __float2bfloat16(f.z), __float2bfloat16(f.w)};
    ((uint2*)d)[i] = *(const uint2*)o;
}
#define CVT_TOTAL4 (4*N4_CC + 2*N4_FC + N4_CC)

// ---- workspace layout (bytes), total ~218 MiB ----
static constexpr size_t SZ_XF32 = (size_t)MROWS*CSZ*4;   // 32 MiB
static constexpr size_t SZ_ABF  = (size_t)MROWS*CSZ*2;   // 16 MiB
static constexpr size_t OFF_X   = 0;
static constexpr size_t OFF_XK  = OFF_X  + SZ_XF32;
static constexpr size_t OFF_XV  = OFF_XK + SZ_ABF;
static constexpr size_t OFF_XR  = OFF_XV + SZ_ABF;
static constexpr size_t OFF_K   = OFF_XR + SZ_ABF;       // k; later rr (bf16)
static constexpr size_t OFF_V   = OFF_K  + SZ_ABF;       // v
static constexpr size_t OFF_R   = OFF_V  + SZ_ABF;       // r
static constexpr size_t OFF_KK  = OFF_R  + SZ_ABF;       // bf16 [M,FFN] 64 MiB; head reused
                                                         // for scan summaries during TimeMixing
static constexpr size_t OFF_W   = OFF_KK + (size_t)MROWS*FFND*2;
static constexpr size_t OFF_WK  = OFF_W;
static constexpr size_t OFF_WV  = OFF_WK + (size_t)CSZ*CSZ*2;
static constexpr size_t OFF_WR  = OFF_WV + (size_t)CSZ*CSZ*2;
static constexpr size_t OFF_WO  = OFF_WR + (size_t)CSZ*CSZ*2;
static constexpr size_t OFF_WCK = OFF_WO + (size_t)CSZ*CSZ*2;
static constexpr size_t OFF_WCV = OFF_WCK + (size_t)FFND*CSZ*2;
static constexpr size_t OFF_WCR = OFF_WCV + (size_t)CSZ*FFND*2;

static constexpr size_t SZ_SUM  = (size_t)BSZ*SCK*CSZ*4; // 1 MiB per array

extern "C" void kernel_launch(void* const* d_in, const int* in_sizes, int n_in,
                              void* d_out, int out_size, void* d_ws, size_t ws_size,
                              hipStream_t stream)
{
    const float* xin   = (const float*)d_in[0];
    const float* ln1w  = (const float*)d_in[1];
    const float* tmixk = (const float*)d_in[2];
    const float* tmixv = (const float*)d_in[3];
    const float* tmixr = (const float*)d_in[4];
    const float* tkw   = (const float*)d_in[5];
    const float* tvw   = (const float*)d_in[6];
    const float* trw   = (const float*)d_in[7];
    const float* tow   = (const float*)d_in[8];
    const float* tdec  = (const float*)d_in[9];
    const float* tfst  = (const float*)d_in[10];
    const float* ln2w  = (const float*)d_in[11];
    const float* cmixk = (const float*)d_in[12];
    const float* cmixr = (const float*)d_in[13];
    const float* ckw   = (const float*)d_in[14];
    const float* cvw   = (const float*)d_in[15];
    const float* crw   = (const float*)d_in[16];
    const float* lnfw  = (const float*)d_in[17];

    char* ws = (char*)d_ws;
    float* xres = (float*)(ws + OFF_X);
    bf16* xk  = (bf16*)(ws + OFF_XK);
    bf16* xv  = (bf16*)(ws + OFF_XV);
    bf16* xr  = (bf16*)(ws + OFF_XR);
    bf16* kb  = (bf16*)(ws + OFF_K);       // k [B,T,C]
    bf16* vb  = (bf16*)(ws + OFF_V);       // v
    bf16* rb  = (bf16*)(ws + OFF_R);       // r (sigmoided)
    bf16* kkb = (bf16*)(ws + OFF_KK);
    bf16* rwkv = xk;                       // xk dead after k GEMM
    bf16* rr  = (bf16*)(ws + OFF_K);       // k dead after scan; rr bf16
    float* sN  = (float*)(ws + OFF_KK);    // kkb dead during TimeMixing
    float* sD  = (float*)(ws + OFF_KK + SZ_SUM);
    float* sM  = (float*)(ws + OFF_KK + 2*SZ_SUM);
    bf16* wk  = (bf16*)(ws + OFF_WK);
    bf16* wv  = (bf16*)(ws + OFF_WV);
    bf16* wr  = (bf16*)(ws + OFF_WR);
    bf16* wo  = (bf16*)(ws + OFF_WO);
    bf16* wck = (bf16*)(ws + OFF_WCK);
    bf16* wcv = (bf16*)(ws + OFF_WCV);
    bf16* wcr = (bf16*)(ws + OFF_WCR);

    const dim3 blk(256);
    const dim3 gKVR(MROWS/BM, CSZ/128, 3);     // (64, 8, 3) = 1536 blocks, 128x128
    const dim3 gC64(MROWS/BM, CSZ/64);         // (64, 16) = 1024 blocks, 128x64
    const dim3 gCMKR(MROWS/BM, FFND/128 + CSZ/128);  // (64, 40) = 2560 blocks
    const dim3 gCMV(MROWS/BM, CSZ/128, 2);     // (64, 8, 2) = 1024 blocks, split-K=2
    const dim3 gScan(SCK, BSZ*4);              // (64, 16)

    for (int l = 0; l < LNUM; ++l) {
        const size_t oC  = (size_t)l*CSZ;
        const size_t oCC = (size_t)l*CSZ*CSZ;
        const size_t oFC = (size_t)l*FFND*CSZ;
        cvt_weights_kernel<<<CVT_TOTAL4/256, blk, 0, stream>>>(
            tkw + oCC, tvw + oCC, trw + oCC, tow + oCC,
            ckw + oFC, cvw + oFC, crw + oCC,
            wk, wv, wr, wo, wck, wcv, wcr);

        // --- TimeMixing ---
        ln_mix_kernel<3><<<MROWS, blk, 0, stream>>>(l == 0 ? xin : xres, ln1w + oC,
            tmixk + oC, tmixv + oC, tmixr + oC, xk, xv, xr);
        gemm_kvr<<<gKVR, blk, 0, stream>>>(xk, xv, xr, wk, wv, wr, kb, vb, rb);
        wkv_sum_kernel<<<gScan, blk, 0, stream>>>(kb, vb, tdec + oC, sN, sD, sM);
        wkv_out_kernel<<<gScan, blk, 0, stream>>>(kb, vb, rb, tdec + oC, tfst + oC,
            sN, sD, sM, rwkv);
        if (l == 0) {
            gemm_bt<6,64><<<gC64, blk, 0, stream>>>(rwkv, wo, xres,
                (const bf16*)xin, CSZ, CSZ, CSZ);
        } else {
            gemm_bt<2,64><<<gC64, blk, 0, stream>>>(rwkv, wo, xres, nullptr,
                CSZ, CSZ, CSZ);
        }

        // --- ChannelMixing ---
        ln_mix_kernel<2><<<MROWS, blk, 0, stream>>>(xres, ln2w + oC,
            cmixk + oC, cmixr + oC, nullptr, xk, xv, nullptr);
        gemm_cmkr<<<gCMKR, blk, 0, stream>>>(xk, xv, wck, wcr, kkb, rr);
        gemm_bt<7,128><<<gCMV, blk, 0, stream>>>(kkb, wcv, xres, rr,
            FFND/2, FFND, CSZ);
    }
    final_ln_kernel<<<MROWS, blk, 0, stream>>>(xres, lnfw, (float*)d_out);
}

// Round 4
// 1721.182 us; speedup vs baseline: 1.0863x; 1.0863x over previous
//
#include <hip/hip_runtime.h>
#include <hip/hip_bf16.h>

// RWKV forward, MI355X gfx950.
// GEMMs: bf16 MFMA 16x16x32, global_load_lds(16B), xor-swizzled LDS,
//   single-buffered m97 structure (R1 dbuf and R3 split-K+atomic both regressed;
//   occupancy/implicit-overlap is the working mechanism at this tile size).
//   - k/v/r merged grid.z=3, 128x128 tiles -> (64,8,3)=1536 blocks
//   - cm_k + cm_r fused one dispatch, 128x128 -> (64,40)=2560 blocks
//   - cm_v: MODE 5, 128x64 -> (64,16)=1024 blocks (proven ~94us; split-K atomic
//     was 135us: 2x RMW write traffic + 24% occupancy)
//   - o-proj: 128x64 (lone N=1024; 128x128 would starve at 512 blocks)
// WKV scan: 2-kernel chunked parallel scan (comb folded into out kernel).
// Layer-0 reads xin directly; o-proj MODE 6 writes xres = xin + acc (no memcpy).

#define LNUM 4
#define BSZ  4
#define TSZ  2048
#define CSZ  1024
#define FFND 4096
#define MROWS (BSZ*TSZ)
#define EPSF 1e-5f

typedef __hip_bfloat16 bf16;
typedef __bf16 bf16x8 __attribute__((ext_vector_type(8)));
typedef float f32x4 __attribute__((ext_vector_type(4)));

#define BM 128
#define BK 64

// scan chunking
#define SCK  64
#define SLEN (TSZ/SCK)   // 32

__device__ __forceinline__ void async_copy16(const void* g, void* l) {
    __builtin_amdgcn_global_load_lds((const __attribute__((address_space(1))) void*)g,
                                     (__attribute__((address_space(3))) void*)l, 16, 0, 0);
}

// ---- shared GEMM body ----
// C[M,N] = A[M,K] * Bw[N,K]^T, bf16 row-major (row stride LDK). TBN=128: 4 waves
// 2x2 of 64x64. TBN=64: 4 waves 4x1 of 32x64. MODE epilogues:
// 2: out f32 += acc              5: out f32 += (float)auxbf[idx] * acc
// 6: out f32 = auxf32[idx] + acc
template<int MODE, int TBN>
__launch_bounds__(256)
__global__ void gemm_bt(const bf16* __restrict__ A, const bf16* __restrict__ Bw,
                        void* __restrict__ outp, const bf16* __restrict__ aux,
                        int K, int LDK, int N)
{
    constexpr int MT  = (TBN == 128) ? 4 : 2;   // 16-row tiles per wave
    constexpr int NBI = TBN / 32;               // B staging issues per thread
    __shared__ __align__(16) __bf16 sA[BM*BK];
    __shared__ __align__(16) __bf16 sB[TBN*BK];
    const int tid  = threadIdx.x;
    const int lane = tid & 63;
    const int wid  = tid >> 6;
    const int wmB  = (TBN == 128) ? (wid >> 1) * 64 : wid * 32;  // wave row base
    const int wnB  = (TBN == 128) ? (wid & 1) * 64 : 0;          // wave col base
    const size_t bm0 = (size_t)blockIdx.x * BM;
    const size_t bn0 = (size_t)blockIdx.y * TBN;

    // staging: 8 lanes/row, 8 chunks of 16B per 64-elem row; xor swizzle.
    const int lrow8 = lane >> 3;
    const int cbg   = (lane & 7) ^ lrow8;

    const bf16* pA[4]; const bf16* pB[NBI];
#pragma unroll
    for (int i = 0; i < 4; ++i)
        pA[i] = A + (bm0 + (i*4 + wid)*8 + lrow8) * (size_t)LDK + cbg*8;
#pragma unroll
    for (int i = 0; i < NBI; ++i)
        pB[i] = Bw + (bn0 + (i*4 + wid)*8 + lrow8) * (size_t)LDK + cbg*8;

    f32x4 acc[MT][4];
#pragma unroll
    for (int a = 0; a < MT; ++a)
#pragma unroll
        for (int b = 0; b < 4; ++b) acc[a][b] = (f32x4){0.f,0.f,0.f,0.f};

    const int q   = lane >> 4;
    const int rlo = lane & 15;

    const int ktiles = K / BK;
    for (int kt = 0; kt < ktiles; ++kt) {
#pragma unroll
        for (int i = 0; i < 4; ++i) {
            async_copy16(pA[i], &sA[(i*4 + wid)*8*BK]);
            pA[i] += BK;
        }
#pragma unroll
        for (int i = 0; i < NBI; ++i) {
            async_copy16(pB[i], &sB[(i*4 + wid)*8*BK]);
            pB[i] += BK;
        }
        __syncthreads();
#pragma unroll
        for (int ks = 0; ks < 2; ++ks) {
            bf16x8 aF[MT], bF[4];
#pragma unroll
            for (int mt = 0; mt < MT; ++mt) {
                const int r  = wmB + mt*16 + rlo;
                const int cb = (ks*4 + q) ^ (r & 7);
                aF[mt] = *(const bf16x8*)&sA[r*BK + cb*8];
            }
#pragma unroll
            for (int nt = 0; nt < 4; ++nt) {
                const int r  = wnB + nt*16 + rlo;
                const int cb = (ks*4 + q) ^ (r & 7);
                bF[nt] = *(const bf16x8*)&sB[r*BK + cb*8];
            }
#pragma unroll
            for (int mt = 0; mt < MT; ++mt)
#pragma unroll
                for (int nt = 0; nt < 4; ++nt)
                    acc[mt][nt] = __builtin_amdgcn_mfma_f32_16x16x32_bf16(
                        aF[mt], bF[nt], acc[mt][nt], 0, 0, 0);
        }
        __syncthreads();
    }

    // C/D layout: col = lane&15, row = (lane>>4)*4 + reg
#pragma unroll
    for (int mt = 0; mt < MT; ++mt) {
#pragma unroll
        for (int nt = 0; nt < 4; ++nt) {
            const size_t col = bn0 + wnB + nt*16 + rlo;
#pragma unroll
            for (int i = 0; i < 4; ++i) {
                const size_t row = bm0 + wmB + mt*16 + q*4 + i;
                const size_t idx = row * (size_t)N + col;
                const float v = acc[mt][nt][i];
                if (MODE == 2) {
                    ((float*)outp)[idx] += v;
                } else if (MODE == 6) {
                    ((float*)outp)[idx] = ((const float*)aux)[idx] + v;
                } else {
                    ((float*)outp)[idx] += (float)aux[idx] * v;
                }
            }
        }
    }
}

// k/v/r GEMMs merged: grid.z selects {A,W,out}; z==2 applies sigmoid. 128x128 tile.
__launch_bounds__(256)
__global__ void gemm_kvr(const bf16* __restrict__ A0, const bf16* __restrict__ A1,
                         const bf16* __restrict__ A2,
                         const bf16* __restrict__ W0, const bf16* __restrict__ W1,
                         const bf16* __restrict__ W2,
                         bf16* __restrict__ O0, bf16* __restrict__ O1,
                         bf16* __restrict__ O2)
{
    constexpr int MT = 4, NBI = 4, K = CSZ, N = CSZ;
    const int z = blockIdx.z;
    const bf16* A  = (z == 0) ? A0 : (z == 1) ? A1 : A2;
    const bf16* Bw = (z == 0) ? W0 : (z == 1) ? W1 : W2;
    bf16* outp     = (z == 0) ? O0 : (z == 1) ? O1 : O2;

    __shared__ __align__(16) __bf16 sA[BM*BK];
    __shared__ __align__(16) __bf16 sB[128*BK];
    const int tid  = threadIdx.x;
    const int lane = tid & 63;
    const int wid  = tid >> 6;
    const int wmB  = (wid >> 1) * 64;
    const int wnB  = (wid & 1) * 64;
    const size_t bm0 = (size_t)blockIdx.x * BM;
    const size_t bn0 = (size_t)blockIdx.y * 128;

    const int lrow8 = lane >> 3;
    const int cbg   = (lane & 7) ^ lrow8;

    const bf16* pA[4]; const bf16* pB[NBI];
#pragma unroll
    for (int i = 0; i < 4; ++i)
        pA[i] = A + (bm0 + (i*4 + wid)*8 + lrow8) * (size_t)K + cbg*8;
#pragma unroll
    for (int i = 0; i < NBI; ++i)
        pB[i] = Bw + (bn0 + (i*4 + wid)*8 + lrow8) * (size_t)K + cbg*8;

    f32x4 acc[MT][4];
#pragma unroll
    for (int a = 0; a < MT; ++a)
#pragma unroll
        for (int b = 0; b < 4; ++b) acc[a][b] = (f32x4){0.f,0.f,0.f,0.f};

    const int q   = lane >> 4;
    const int rlo = lane & 15;

    for (int kt = 0; kt < K/BK; ++kt) {
#pragma unroll
        for (int i = 0; i < 4; ++i) {
            async_copy16(pA[i], &sA[(i*4 + wid)*8*BK]);
            pA[i] += BK;
        }
#pragma unroll
        for (int i = 0; i < NBI; ++i) {
            async_copy16(pB[i], &sB[(i*4 + wid)*8*BK]);
            pB[i] += BK;
        }
        __syncthreads();
#pragma unroll
        for (int ks = 0; ks < 2; ++ks) {
            bf16x8 aF[MT], bF[4];
#pragma unroll
            for (int mt = 0; mt < MT; ++mt) {
                const int r  = wmB + mt*16 + rlo;
                const int cb = (ks*4 + q) ^ (r & 7);
                aF[mt] = *(const bf16x8*)&sA[r*BK + cb*8];
            }
#pragma unroll
            for (int nt = 0; nt < 4; ++nt) {
                const int r  = wnB + nt*16 + rlo;
                const int cb = (ks*4 + q) ^ (r & 7);
                bF[nt] = *(const bf16x8*)&sB[r*BK + cb*8];
            }
#pragma unroll
            for (int mt = 0; mt < MT; ++mt)
#pragma unroll
                for (int nt = 0; nt < 4; ++nt)
                    acc[mt][nt] = __builtin_amdgcn_mfma_f32_16x16x32_bf16(
                        aF[mt], bF[nt], acc[mt][nt], 0, 0, 0);
        }
        __syncthreads();
    }

#pragma unroll
    for (int mt = 0; mt < MT; ++mt) {
#pragma unroll
        for (int nt = 0; nt < 4; ++nt) {
            const size_t col = bn0 + wnB + nt*16 + rlo;
#pragma unroll
            for (int i = 0; i < 4; ++i) {
                const size_t row = bm0 + wmB + mt*16 + q*4 + i;
                float v = acc[mt][nt][i];
                if (z == 2) v = 1.f/(1.f+__expf(-v));
                ((bf16*)outp)[row * (size_t)N + col] = __float2bfloat16(v);
            }
        }
    }
}

// cm_k (N=4096, relu^2) and cm_r (N=1024, sigmoid) fused: blockIdx.y<32 -> cm_k,
// else cm_r. Both 128x128, K=1024. Independent (both read ln2 outputs).
__launch_bounds__(256)
__global__ void gemm_cmkr(const bf16* __restrict__ Ak, const bf16* __restrict__ Ar,
                          const bf16* __restrict__ Wk, const bf16* __restrict__ Wr,
                          bf16* __restrict__ Ok, bf16* __restrict__ Or)
{
    constexpr int MT = 4, NBI = 4, K = CSZ;
    const bool isk = (blockIdx.y < FFND/128);
    const bf16* A  = isk ? Ak : Ar;
    const bf16* Bw = isk ? Wk : Wr;
    bf16* outp     = isk ? Ok : Or;
    const int N    = isk ? FFND : CSZ;
    const size_t bn0 = (size_t)(isk ? blockIdx.y : blockIdx.y - FFND/128) * 128;

    __shared__ __align__(16) __bf16 sA[BM*BK];
    __shared__ __align__(16) __bf16 sB[128*BK];
    const int tid  = threadIdx.x;
    const int lane = tid & 63;
    const int wid  = tid >> 6;
    const int wmB  = (wid >> 1) * 64;
    const int wnB  = (wid & 1) * 64;
    const size_t bm0 = (size_t)blockIdx.x * BM;

    const int lrow8 = lane >> 3;
    const int cbg   = (lane & 7) ^ lrow8;

    const bf16* pA[4]; const bf16* pB[NBI];
#pragma unroll
    for (int i = 0; i < 4; ++i)
        pA[i] = A + (bm0 + (i*4 + wid)*8 + lrow8) * (size_t)K + cbg*8;
#pragma unroll
    for (int i = 0; i < NBI; ++i)
        pB[i] = Bw + (bn0 + (i*4 + wid)*8 + lrow8) * (size_t)K + cbg*8;

    f32x4 acc[MT][4];
#pragma unroll
    for (int a = 0; a < MT; ++a)
#pragma unroll
        for (int b = 0; b < 4; ++b) acc[a][b] = (f32x4){0.f,0.f,0.f,0.f};

    const int q   = lane >> 4;
    const int rlo = lane & 15;

    for (int kt = 0; kt < K/BK; ++kt) {
#pragma unroll
        for (int i = 0; i < 4; ++i) {
            async_copy16(pA[i], &sA[(i*4 + wid)*8*BK]);
            pA[i] += BK;
        }
#pragma unroll
        for (int i = 0; i < NBI; ++i) {
            async_copy16(pB[i], &sB[(i*4 + wid)*8*BK]);
            pB[i] += BK;
        }
        __syncthreads();
#pragma unroll
        for (int ks = 0; ks < 2; ++ks) {
            bf16x8 aF[MT], bF[4];
#pragma unroll
            for (int mt = 0; mt < MT; ++mt) {
                const int r  = wmB + mt*16 + rlo;
                const int cb = (ks*4 + q) ^ (r & 7);
                aF[mt] = *(const bf16x8*)&sA[r*BK + cb*8];
            }
#pragma unroll
            for (int nt = 0; nt < 4; ++nt) {
                const int r  = wnB + nt*16 + rlo;
                const int cb = (ks*4 + q) ^ (r & 7);
                bF[nt] = *(const bf16x8*)&sB[r*BK + cb*8];
            }
#pragma unroll
            for (int mt = 0; mt < MT; ++mt)
#pragma unroll
                for (int nt = 0; nt < 4; ++nt)
                    acc[mt][nt] = __builtin_amdgcn_mfma_f32_16x16x32_bf16(
                        aF[mt], bF[nt], acc[mt][nt], 0, 0, 0);
        }
        __syncthreads();
    }

#pragma unroll
    for (int mt = 0; mt < MT; ++mt) {
#pragma unroll
        for (int nt = 0; nt < 4; ++nt) {
            const size_t col = bn0 + wnB + nt*16 + rlo;
#pragma unroll
            for (int i = 0; i < 4; ++i) {
                const size_t row = bm0 + wmB + mt*16 + q*4 + i;
                const float v = acc[mt][nt][i];
                float o;
                if (isk) { const float t = fmaxf(v, 0.f); o = t*t; }
                else     { o = 1.f/(1.f+__expf(-v)); }
                ((bf16*)outp)[row * (size_t)N + col] = __float2bfloat16(o);
            }
        }
    }
}

// Fused LayerNorm + time_shift + token mixes. Block = one (b,t) row, 256 thr x 4 ch.
template<int NOUT>
__launch_bounds__(256)
__global__ void ln_mix_kernel(const float* __restrict__ x, const float* __restrict__ lnw,
                              const float* __restrict__ mka, const float* __restrict__ mva,
                              const float* __restrict__ mra,
                              bf16* __restrict__ ok, bf16* __restrict__ ov, bf16* __restrict__ orr)
{
    const int bt  = blockIdx.x;
    const int t   = bt % TSZ;
    const int tid = threadIdx.x;
    const float4 xc = ((const float4*)(x + (size_t)bt*CSZ))[tid];
    float4 xp = {0.f,0.f,0.f,0.f};
    const bool hasp = (t != 0);
    if (hasp) xp = ((const float4*)(x + (size_t)(bt-1)*CSZ))[tid];

    float s0 = xc.x+xc.y+xc.z+xc.w;
    float s1 = xc.x*xc.x+xc.y*xc.y+xc.z*xc.z+xc.w*xc.w;
    float s2 = xp.x+xp.y+xp.z+xp.w;
    float s3 = xp.x*xp.x+xp.y*xp.y+xp.z*xp.z+xp.w*xp.w;
#pragma unroll
    for (int off = 32; off > 0; off >>= 1) {
        s0 += __shfl_down(s0, off); s1 += __shfl_down(s1, off);
        s2 += __shfl_down(s2, off); s3 += __shfl_down(s3, off);
    }
    __shared__ float red[4][4];
    if ((tid & 63) == 0) { const int wq = tid >> 6;
        red[wq][0]=s0; red[wq][1]=s1; red[wq][2]=s2; red[wq][3]=s3; }
    __syncthreads();
    s0 = red[0][0]+red[1][0]+red[2][0]+red[3][0];
    s1 = red[0][1]+red[1][1]+red[2][1]+red[3][1];
    s2 = red[0][2]+red[1][2]+red[2][2]+red[3][2];
    s3 = red[0][3]+red[1][3]+red[2][3]+red[3][3];

    const float inv = 1.f/CSZ;
    const float muC = s0*inv;
    const float rsC = rsqrtf(s1*inv - muC*muC + EPSF);
    const float muP = s2*inv;
    const float rsP = rsqrtf(s3*inv - muP*muP + EPSF);

    const int c4 = tid*4;
    const float4 lw = ((const float4*)lnw)[tid];
    const float4 mk = ((const float4*)mka)[tid];
    const float4 mv = (NOUT >= 2) ? ((const float4*)mva)[tid] : lw;
    const float4 mr = (NOUT >= 3) ? ((const float4*)mra)[tid] : lw;

    float hcv[4] = {(xc.x-muC)*rsC*lw.x, (xc.y-muC)*rsC*lw.y,
                    (xc.z-muC)*rsC*lw.z, (xc.w-muC)*rsC*lw.w};
    float hpv[4];
    if (hasp) {
        hpv[0]=(xp.x-muP)*rsP*lw.x; hpv[1]=(xp.y-muP)*rsP*lw.y;
        hpv[2]=(xp.z-muP)*rsP*lw.z; hpv[3]=(xp.w-muP)*rsP*lw.w;
    } else { hpv[0]=hpv[1]=hpv[2]=hpv[3]=0.f; }
    const float mkv[4]={mk.x,mk.y,mk.z,mk.w};
    const float mvv[4]={mv.x,mv.y,mv.z,mv.w};
    const float mrv[4]={mr.x,mr.y,mr.z,mr.w};

    __align__(8) bf16 o0[4], o1[4], o2[4];
#pragma unroll
    for (int j = 0; j < 4; ++j) {
        o0[j] = __float2bfloat16(hcv[j]*mkv[j] + hpv[j]*(1.f-mkv[j]));
        if (NOUT >= 2) o1[j] = __float2bfloat16(hcv[j]*mvv[j] + hpv[j]*(1.f-mvv[j]));
        if (NOUT >= 3) o2[j] = __float2bfloat16(hcv[j]*mrv[j] + hpv[j]*(1.f-mrv[j]));
    }
    *(uint2*)(ok + (size_t)bt*CSZ + c4) = *(const uint2*)o0;
    if (NOUT >= 2) *(uint2*)(ov  + (size_t)bt*CSZ + c4) = *(const uint2*)o1;
    if (NOUT >= 3) *(uint2*)(orr + (size_t)bt*CSZ + c4) = *(const uint2*)o2;
}

// ---- WKV 2-kernel chunked parallel scan, channels-along-lanes ----
__launch_bounds__(256)
__global__ void wkv_sum_kernel(const bf16* __restrict__ kb, const bf16* __restrict__ vb,
                               const float* __restrict__ td,
                               float* __restrict__ sN, float* __restrict__ sD,
                               float* __restrict__ sM)
{
    const int j  = blockIdx.x;
    const int b  = blockIdx.y >> 2;
    const int cg = blockIdx.y & 3;
    const int c  = cg*256 + threadIdx.x;
    const float w = -__expf(td[c]);

    size_t idx = ((size_t)b*TSZ + j*SLEN)*CSZ + c;
    float num = 0.f, den = 0.f, mx = -1e38f;
    float kt = (float)kb[idx], vt = (float)vb[idx];
    for (int t = 0; t < SLEN; ++t) {
        float kn = 0.f, vn = 0.f;
        if (t + 1 < SLEN) {
            kn = (float)kb[idx + CSZ]; vn = (float)vb[idx + CSZ];
        }
        const float ms = fmaxf(mx + w, kt);
        const float p1 = __expf(mx + w - ms);
        const float p2 = __expf(kt - ms);
        num = p1*num + p2*vt; den = p1*den + p2; mx = ms;
        idx += CSZ; kt = kn; vt = vn;
    }
    const size_t sidx = ((size_t)b*SCK + j)*CSZ + c;
    sN[sidx] = num; sD[sidx] = den; sM[sidx] = mx;
}

// Out kernel computes its own exclusive prefix over chunk summaries (comb folded in).
__launch_bounds__(256)
__global__ void wkv_out_kernel(const bf16* __restrict__ kb, const bf16* __restrict__ vb,
                               const bf16* __restrict__ rb,
                               const float* __restrict__ td, const float* __restrict__ tf,
                               const float* __restrict__ sN, const float* __restrict__ sD,
                               const float* __restrict__ sM,
                               bf16* __restrict__ outb)
{
    const int j  = blockIdx.x;
    const int b  = blockIdx.y >> 2;
    const int cg = blockIdx.y & 3;
    const int c  = cg*256 + threadIdx.x;
    const float w = -__expf(td[c]);
    const float u = tf[c];
    const float wL = w * (float)SLEN;

    // exclusive prefix over chunks 0..j-1
    float num = 0.f, den = 0.f, mx = -1e38f;
    size_t pidx = (size_t)b*SCK*CSZ + c;
    for (int jj = 0; jj < j; ++jj) {
        const float nl = sN[pidx], dl = sD[pidx], ml = sM[pidx];
        const float mi = mx + wL;
        const float mo = fmaxf(mi, ml);
        const float e1 = __expf(mi - mo);
        const float e2 = __expf(ml - mo);
        num = e1*num + e2*nl; den = e1*den + e2*dl; mx = mo;
        pidx += CSZ;
    }

    size_t idx = ((size_t)b*TSZ + j*SLEN)*CSZ + c;
    float kt = (float)kb[idx], vt = (float)vb[idx], rt = (float)rb[idx];
    for (int t = 0; t < SLEN; ++t) {
        float kn = 0.f, vn = 0.f, rn = 0.f;
        if (t + 1 < SLEN) {
            kn = (float)kb[idx + CSZ]; vn = (float)vb[idx + CSZ]; rn = (float)rb[idx + CSZ];
        }
        const float ku = kt + u;
        const float mo = fmaxf(mx, ku);
        const float e1 = __expf(mx - mo);
        const float e2 = __expf(ku - mo);
        const float outv = (e1*num + e2*vt) / (e1*den + e2);
        const float ms = fmaxf(mx + w, kt);
        const float p1 = __expf(mx + w - ms);
        const float p2 = __expf(kt - ms);
        num = p1*num + p2*vt; den = p1*den + p2; mx = ms;
        outb[idx] = __float2bfloat16(rt * outv);
        idx += CSZ; kt = kn; vt = vn; rt = rn;
    }
}

__launch_bounds__(256)
__global__ void final_ln_kernel(const float* __restrict__ x, const float* __restrict__ lnw,
                                float* __restrict__ out)
{
    const int bt  = blockIdx.x;
    const int tid = threadIdx.x;
    const float4 xc = ((const float4*)(x + (size_t)bt*CSZ))[tid];
    float s0 = xc.x+xc.y+xc.z+xc.w;
    float s1 = xc.x*xc.x+xc.y*xc.y+xc.z*xc.z+xc.w*xc.w;
#pragma unroll
    for (int off = 32; off > 0; off >>= 1) {
        s0 += __shfl_down(s0, off); s1 += __shfl_down(s1, off);
    }
    __shared__ float red[4][2];
    if ((tid & 63) == 0) { red[tid>>6][0] = s0; red[tid>>6][1] = s1; }
    __syncthreads();
    s0 = red[0][0]+red[1][0]+red[2][0]+red[3][0];
    s1 = red[0][1]+red[1][1]+red[2][1]+red[3][1];
    const float inv = 1.f/CSZ;
    const float mu = s0*inv;
    const float rs = rsqrtf(s1*inv - mu*mu + EPSF);
    const float4 lw = ((const float4*)lnw)[tid];
    float4 o;
    o.x = (xc.x-mu)*rs*lw.x; o.y = (xc.y-mu)*rs*lw.y;
    o.z = (xc.z-mu)*rs*lw.z; o.w = (xc.w-mu)*rs*lw.w;
    ((float4*)(out + (size_t)bt*CSZ))[tid] = o;
}

// One fused per-layer weight conversion (7 tensors -> bf16). Units of 4 elems.
#define N4_CC (CSZ*CSZ/4)
#define N4_FC (FFND*CSZ/4)
__global__ void cvt_weights_kernel(const float* __restrict__ tk, const float* __restrict__ tv,
                                   const float* __restrict__ tr, const float* __restrict__ to,
                                   const float* __restrict__ ck, const float* __restrict__ cv,
                                   const float* __restrict__ cr,
                                   bf16* __restrict__ wk, bf16* __restrict__ wv,
                                   bf16* __restrict__ wr, bf16* __restrict__ wo,
                                   bf16* __restrict__ wck, bf16* __restrict__ wcv,
                                   bf16* __restrict__ wcr)
{
    int i = blockIdx.x * 256 + threadIdx.x;
    const float* s; bf16* d;
    if      (i < 1*N4_CC)          { s = tk; d = wk;  }
    else if (i < 2*N4_CC)          { s = tv; d = wv;  i -= 1*N4_CC; }
    else if (i < 3*N4_CC)          { s = tr; d = wr;  i -= 2*N4_CC; }
    else if (i < 4*N4_CC)          { s = to; d = wo;  i -= 3*N4_CC; }
    else if (i < 4*N4_CC+N4_FC)    { s = ck; d = wck; i -= 4*N4_CC; }
    else if (i < 4*N4_CC+2*N4_FC)  { s = cv; d = wcv; i -= 4*N4_CC+N4_FC; }
    else                           { s = cr; d = wcr; i -= 4*N4_CC+2*N4_FC; }
    const float4 f = ((const float4*)s)[i];
    __align__(8) bf16 o[4] = {__float2bfloat16(f.x), __float2bfloat16(f.y),
                              __float2bfloat16(f.z), __float2bfloat16(f.w)};
    ((uint2*)d)[i] = *(const uint2*)o;
}
#define CVT_TOTAL4 (4*N4_CC + 2*N4_FC + N4_CC)

// ---- workspace layout (bytes), total ~218 MiB ----
static constexpr size_t SZ_XF32 = (size_t)MROWS*CSZ*4;   // 32 MiB
static constexpr size_t SZ_ABF  = (size_t)MROWS*CSZ*2;   // 16 MiB
static constexpr size_t OFF_X   = 0;
static constexpr size_t OFF_XK  = OFF_X  + SZ_XF32;
static constexpr size_t OFF_XV  = OFF_XK + SZ_ABF;
static constexpr size_t OFF_XR  = OFF_XV + SZ_ABF;
static constexpr size_t OFF_K   = OFF_XR + SZ_ABF;       // k; later rr (bf16)
static constexpr size_t OFF_V   = OFF_K  + SZ_ABF;       // v
static constexpr size_t OFF_R   = OFF_V  + SZ_ABF;       // r
static constexpr size_t OFF_KK  = OFF_R  + SZ_ABF;       // bf16 [M,FFN] 64 MiB; head reused
                                                         // for scan summaries during TimeMixing
static constexpr size_t OFF_W   = OFF_KK + (size_t)MROWS*FFND*2;
static constexpr size_t OFF_WK  = OFF_W;
static constexpr size_t OFF_WV  = OFF_WK + (size_t)CSZ*CSZ*2;
static constexpr size_t OFF_WR  = OFF_WV + (size_t)CSZ*CSZ*2;
static constexpr size_t OFF_WO  = OFF_WR + (size_t)CSZ*CSZ*2;
static constexpr size_t OFF_WCK = OFF_WO + (size_t)CSZ*CSZ*2;
static constexpr size_t OFF_WCV = OFF_WCK + (size_t)FFND*CSZ*2;
static constexpr size_t OFF_WCR = OFF_WCV + (size_t)CSZ*FFND*2;

static constexpr size_t SZ_SUM  = (size_t)BSZ*SCK*CSZ*4; // 1 MiB per array

extern "C" void kernel_launch(void* const* d_in, const int* in_sizes, int n_in,
                              void* d_out, int out_size, void* d_ws, size_t ws_size,
                              hipStream_t stream)
{
    const float* xin   = (const float*)d_in[0];
    const float* ln1w  = (const float*)d_in[1];
    const float* tmixk = (const float*)d_in[2];
    const float* tmixv = (const float*)d_in[3];
    const float* tmixr = (const float*)d_in[4];
    const float* tkw   = (const float*)d_in[5];
    const float* tvw   = (const float*)d_in[6];
    const float* trw   = (const float*)d_in[7];
    const float* tow   = (const float*)d_in[8];
    const float* tdec  = (const float*)d_in[9];
    const float* tfst  = (const float*)d_in[10];
    const float* ln2w  = (const float*)d_in[11];
    const float* cmixk = (const float*)d_in[12];
    const float* cmixr = (const float*)d_in[13];
    const float* ckw   = (const float*)d_in[14];
    const float* cvw   = (const float*)d_in[15];
    const float* crw   = (const float*)d_in[16];
    const float* lnfw  = (const float*)d_in[17];

    char* ws = (char*)d_ws;
    float* xres = (float*)(ws + OFF_X);
    bf16* xk  = (bf16*)(ws + OFF_XK);
    bf16* xv  = (bf16*)(ws + OFF_XV);
    bf16* xr  = (bf16*)(ws + OFF_XR);
    bf16* kb  = (bf16*)(ws + OFF_K);       // k [B,T,C]
    bf16* vb  = (bf16*)(ws + OFF_V);       // v
    bf16* rb  = (bf16*)(ws + OFF_R);       // r (sigmoided)
    bf16* kkb = (bf16*)(ws + OFF_KK);
    bf16* rwkv = xk;                       // xk dead after k GEMM
    bf16* rr  = (bf16*)(ws + OFF_K);       // k dead after scan; rr bf16
    float* sN  = (float*)(ws + OFF_KK);    // kkb dead during TimeMixing
    float* sD  = (float*)(ws + OFF_KK + SZ_SUM);
    float* sM  = (float*)(ws + OFF_KK + 2*SZ_SUM);
    bf16* wk  = (bf16*)(ws + OFF_WK);
    bf16* wv  = (bf16*)(ws + OFF_WV);
    bf16* wr  = (bf16*)(ws + OFF_WR);
    bf16* wo  = (bf16*)(ws + OFF_WO);
    bf16* wck = (bf16*)(ws + OFF_WCK);
    bf16* wcv = (bf16*)(ws + OFF_WCV);
    bf16* wcr = (bf16*)(ws + OFF_WCR);

    const dim3 blk(256);
    const dim3 gKVR(MROWS/BM, CSZ/128, 3);     // (64, 8, 3) = 1536 blocks, 128x128
    const dim3 gC64(MROWS/BM, CSZ/64);         // (64, 16) = 1024 blocks, 128x64
    const dim3 gCMKR(MROWS/BM, FFND/128 + CSZ/128);  // (64, 40) = 2560 blocks
    const dim3 gScan(SCK, BSZ*4);              // (64, 16)

    for (int l = 0; l < LNUM; ++l) {
        const size_t oC  = (size_t)l*CSZ;
        const size_t oCC = (size_t)l*CSZ*CSZ;
        const size_t oFC = (size_t)l*FFND*CSZ;
        cvt_weights_kernel<<<CVT_TOTAL4/256, blk, 0, stream>>>(
            tkw + oCC, tvw + oCC, trw + oCC, tow + oCC,
            ckw + oFC, cvw + oFC, crw + oCC,
            wk, wv, wr, wo, wck, wcv, wcr);

        // --- TimeMixing ---
        ln_mix_kernel<3><<<MROWS, blk, 0, stream>>>(l == 0 ? xin : xres, ln1w + oC,
            tmixk + oC, tmixv + oC, tmixr + oC, xk, xv, xr);
        gemm_kvr<<<gKVR, blk, 0, stream>>>(xk, xv, xr, wk, wv, wr, kb, vb, rb);
        wkv_sum_kernel<<<gScan, blk, 0, stream>>>(kb, vb, tdec + oC, sN, sD, sM);
        wkv_out_kernel<<<gScan, blk, 0, stream>>>(kb, vb, rb, tdec + oC, tfst + oC,
            sN, sD, sM, rwkv);
        if (l == 0) {
            gemm_bt<6,64><<<gC64, blk, 0, stream>>>(rwkv, wo, xres,
                (const bf16*)xin, CSZ, CSZ, CSZ);
        } else {
            gemm_bt<2,64><<<gC64, blk, 0, stream>>>(rwkv, wo, xres, nullptr,
                CSZ, CSZ, CSZ);
        }

        // --- ChannelMixing ---
        ln_mix_kernel<2><<<MROWS, blk, 0, stream>>>(xres, ln2w + oC,
            cmixk + oC, cmixr + oC, nullptr, xk, xv, nullptr);
        gemm_cmkr<<<gCMKR, blk, 0, stream>>>(xk, xv, wck, wcr, kkb, rr);
        gemm_bt<5,64><<<gC64, blk, 0, stream>>>(kkb, wcv, xres, rr,
            FFND, FFND, CSZ);
    }
    final_ln_kernel<<<MROWS, blk, 0, stream>>>(xres, lnfw, (float*)d_out);
}